// Round 2
// baseline (431.742 us; speedup 1.0000x reference)
//
#include <hip/hip_runtime.h>
#include <hip/hip_bf16.h>
#include <stdint.h>

// ---------------------------------------------------------------------------
// AttentionBlock: y = Attn(RoPE(x@wq^T), RoPE(x@wk^T), x@wv^T) @ wo^T
// B=2 T=2048 D=2048 H=32 HD=64. FP32 in/out, bf16 MFMA internal.
//
// r5 (resubmit of r5/r0-proposal after infra-flake container failure; kernel
// re-audited: uniform barriers -> no deadlock; all global/LDS addresses
// bounds-checked; peak ~230 VGPR < 256):
//  - gemm_qkv: 256x256 / BK=64 / 8-wave 8-phase kernel (m201 structure):
//    T1 bijective XCD swizzle, T2 st_16x32 LDS swizzle (inverse-swizzled
//    global src -> linear global_load_lds dest -> swizzled ds_read_b128),
//    T3+T4 counted vmcnt(4) only at phase 4/8 (never 0 in loop), T5
//    setprio(1) around each 16-MFMA cluster. 128KiB LDS dbuf.
//  - RoPE (+0.125 q-scale) fused into the gemm epilogue via __shfl_xor(v,1)
//    lane pairing; rope_kernel dispatch removed from Path A.
// ---------------------------------------------------------------------------

typedef __bf16 bf16_t;
typedef __bf16 bf16x4 __attribute__((ext_vector_type(4)));
typedef __bf16 bf16x8 __attribute__((ext_vector_type(8)));
typedef float  f32x4  __attribute__((ext_vector_type(4)));

constexpr int B_ = 2, T_ = 2048, D_ = 2048, H_ = 32, HD_ = 64;
constexpr int M_ = B_ * T_;   // 4096 token rows

// async global->LDS, 16B per lane; LDS dest = wave-uniform base + lane*16
__device__ __forceinline__ void async_copy16(const bf16_t* g, bf16_t* l) {
  __builtin_amdgcn_global_load_lds(
      (const __attribute__((address_space(1))) void*)g,
      (__attribute__((address_space(3))) void*)l, 16, 0, 0);
}

// ---------------------------------------------------------------------------
// f32 -> bf16 cast, 4 elements/thread.
// ---------------------------------------------------------------------------
__global__ __launch_bounds__(256) void cast_f32_bf16(
    const float* __restrict__ src, bf16_t* __restrict__ dst, int n4)
{
  const int i = blockIdx.x * 256 + threadIdx.x;
  if (i >= n4) return;
  const float4 v = ((const float4*)src)[i];
  bf16x4 o;
  o[0] = (bf16_t)v.x; o[1] = (bf16_t)v.y; o[2] = (bf16_t)v.z; o[3] = (bf16_t)v.w;
  ((bf16x4*)dst)[i] = o;
}

// ---------------------------------------------------------------------------
// GEMM: C[M][N] = A[M][K] . B[N][K]^T — m97 structure (kept for wo-gemm and
// Path B fallback).
// ---------------------------------------------------------------------------
template <typename OutT>
__global__ __launch_bounds__(256, 2) void gemm_bt(
    const bf16_t* __restrict__ A, const bf16_t* __restrict__ B,
    OutT* __restrict__ C, int M, int N, int K)
{
  __shared__ __attribute__((aligned(16))) bf16_t As[128 * 32];
  __shared__ __attribute__((aligned(16))) bf16_t Bs[128 * 32];

  const int tid    = threadIdx.x;
  const int w      = tid >> 6;
  const int l      = tid & 63;
  const int quad   = l >> 4;
  const int lane16 = l & 15;
  const int bm0 = blockIdx.x * 128;
  const int bn0 = blockIdx.y * 128;
  const int wm  = (w >> 1) * 64;
  const int wn  = (w & 1) * 64;
  const int srow = l >> 2;
  const int scol = (l & 3) * 8;

  const bf16_t* Ag = A + (size_t)bm0 * K;
  const bf16_t* Bg = B + (size_t)bn0 * K;

  f32x4 acc[4][4] = {};

  for (int kk = 0; kk < K; kk += 32) {
    __syncthreads();
#pragma unroll
    for (int s0 = 0; s0 < 2; ++s0) {
      const int s = w + s0 * 4;
      async_copy16(Ag + (size_t)(s * 16 + srow) * K + kk + scol, &As[s * 512]);
      async_copy16(Bg + (size_t)(s * 16 + srow) * K + kk + scol, &Bs[s * 512]);
    }
    __syncthreads();

    bf16x8 af[4], bfr[4];
#pragma unroll
    for (int i = 0; i < 4; ++i)
      af[i] = *(const bf16x8*)&As[(wm + i * 16 + lane16) * 32 + quad * 8];
#pragma unroll
    for (int j = 0; j < 4; ++j)
      bfr[j] = *(const bf16x8*)&Bs[(wn + j * 16 + lane16) * 32 + quad * 8];
#pragma unroll
    for (int i = 0; i < 4; ++i)
#pragma unroll
      for (int j = 0; j < 4; ++j)
        acc[i][j] = __builtin_amdgcn_mfma_f32_16x16x32_bf16(af[i], bfr[j],
                                                            acc[i][j], 0, 0, 0);
  }

#pragma unroll
  for (int i = 0; i < 4; ++i) {
#pragma unroll
    for (int r = 0; r < 4; ++r) {
      const size_t row = (size_t)(bm0 + wm + i * 16 + quad * 4 + r);
#pragma unroll
      for (int j = 0; j < 4; ++j) {
        const int col = bn0 + wn + j * 16 + lane16;
        C[row * N + col] = (OutT)acc[i][j][r];
      }
    }
  }
}

// ---------------------------------------------------------------------------
// 8-phase 256x256 merged-QKV GEMM helpers.
// LDS half-tile layout: 128 rows x 64 cols bf16 = 16KB, organized as 16
// subtiles (8 row-groups x 2 col-groups) of 16x32, 1024B each; within a
// subtile byte = r4*64 + cg*16 with swizzle cg_stored = cg ^ ((r4>>3)<<1)
// (st_16x32: byte ^= ((byte>>9)&1)<<5). global_load_lds writes granules
// linearly; the global source address is inverse-swizzled to compensate.
// ---------------------------------------------------------------------------
template <int I0>
__device__ __forceinline__ void rd4(const char* p, bf16x8 (&a)[4][2]) {
#pragma unroll
  for (int i = 0; i < 4; ++i)
#pragma unroll
    for (int ks = 0; ks < 2; ++ks)
      a[i][ks] = *(const bf16x8*)(p + (((I0 + i) * 2 + ks) << 10));
}

template <int J0>
__device__ __forceinline__ void rd2(const char* p, bf16x8 (&b)[2][2]) {
#pragma unroll
  for (int j = 0; j < 2; ++j)
#pragma unroll
    for (int ks = 0; ks < 2; ++ks)
      b[j][ks] = *(const bf16x8*)(p + (((J0 + j) * 2 + ks) << 10));
}

template <int I0, int J0>
__device__ __forceinline__ void mm16(f32x4 (&acc)[8][4],
                                     const bf16x8 (&a)[4][2],
                                     const bf16x8 (&b)[2][2]) {
  __builtin_amdgcn_s_setprio(1);
#pragma unroll
  for (int i = 0; i < 4; ++i)
#pragma unroll
    for (int j = 0; j < 2; ++j)
#pragma unroll
      for (int ks = 0; ks < 2; ++ks)
        acc[I0 + i][J0 + j] = __builtin_amdgcn_mfma_f32_16x16x32_bf16(
            a[i][ks], b[j][ks], acc[I0 + i][J0 + j], 0, 0, 0);
  __builtin_amdgcn_s_setprio(0);
}

#define GQ_BAR()   __builtin_amdgcn_s_barrier()
#define GQ_LGKM0() asm volatile("s_waitcnt lgkmcnt(0)" ::: "memory")
#define GQ_FENCE() asm volatile("" ::: "memory")

// ---------------------------------------------------------------------------
// Merged-QKV GEMM, 256x256 tile, BK=64, 512 threads (8 waves, 2Mx4N),
// 8-phase counted-vmcnt schedule, fused RoPE epilogue.
// A[M=4096][2048], Bw = concat(wq|wk|wv) [6144][2048]. Grid: 384 blocks.
// ---------------------------------------------------------------------------
__global__ __launch_bounds__(512, 2) void gemm_qkv8(
    const bf16_t* __restrict__ A, const bf16_t* __restrict__ Bw,
    bf16_t* __restrict__ Cq, bf16_t* __restrict__ Ck, bf16_t* __restrict__ Cv,
    const float* __restrict__ fc, const float* __restrict__ fs)
{
  __shared__ __attribute__((aligned(16))) bf16_t lds[65536];  // 128 KiB
  constexpr int K = 2048;

  const int tid    = threadIdx.x;
  const int w      = tid >> 6;
  const int l      = tid & 63;
  const int quad   = l >> 4;
  const int lane16 = l & 15;
  const int wr = w >> 2;      // 0..1 : 128-row strip
  const int wc = w & 3;       // 0..3 : 64-col strip

  // T1: bijective XCD swizzle (384 % 8 == 0). lin = bn*16 + bm.
  const int lin = (blockIdx.x & 7) * 48 + (blockIdx.x >> 3);
  const int bm0 = (lin & 15) << 8;
  const int bn0 = (lin >> 4) << 8;

  // per-thread staging offsets (granule g = c*512 + tid, 16B each)
  size_t so[2]; int lo[2];
#pragma unroll
  for (int c = 0; c < 2; ++c) {
    const int g  = c * 512 + tid;
    const int st = g >> 6, r4 = (g >> 2) & 15, cgs = g & 3;
    const int cg = cgs ^ (((r4 >> 3) & 1) << 1);           // inverse swizzle
    so[c] = (size_t)(((st >> 1) << 4) + r4) * K + ((st & 1) << 5) + (cg << 3);
    lo[c] = (c * 512 + (w << 6)) * 8;                      // wave-uniform
  }

  const bf16_t* Ag = A  + (size_t)bm0 * K;
  const bf16_t* Bg = Bw + (size_t)bn0 * K;

  auto stA = [&](int half, int kt, int db) {
    const bf16_t* gb = Ag + (size_t)(half << 7) * K + (kt << 6);
    bf16_t* lb = &lds[((db << 1) + half) << 13];
    async_copy16(gb + so[0], lb + lo[0]);
    async_copy16(gb + so[1], lb + lo[1]);
  };
  auto stB = [&](int half, int kt, int db) {
    const bf16_t* gb = Bg + (size_t)(half << 7) * K + (kt << 6);
    bf16_t* lb = &lds[32768 + (((db << 1) + half) << 13)];
    async_copy16(gb + so[0], lb + lo[0]);
    async_copy16(gb + so[1], lb + lo[1]);
  };

  // fragment read base (swizzled): r4 = lane16, cg = quad
  const int rbase = lane16 * 64 + ((quad ^ (((lane16 >> 3) & 1) << 1)) << 4);
  const char* pAl = (const char*)lds + wr * 16384 + rbase;
  const char* pBl = (const char*)lds + 65536 + ((wc >> 1) * 16384) +
                    ((wc & 1) * 8192) + rbase;

  f32x4 acc[8][4] = {};

  // prologue: K-tile 0 (all 4 half-tiles) + A halves of K-tile 1
  stA(0, 0, 0); stA(1, 0, 0); stB(0, 0, 0); stB(1, 0, 0);
  stA(0, 1, 1); stA(1, 1, 1);
  asm volatile("s_waitcnt vmcnt(4)" ::: "memory");
  GQ_BAR();
  GQ_FENCE();

#pragma unroll 1
  for (int it = 0; it < 16; ++it) {
    const int ktB = 2 * it + 1;                               // <= 31 always
    const int kt2 = (2 * it + 2 < 32) ? 2 * it + 2 : 31;      // addr clamp
    const int kt3 = (2 * it + 3 < 32) ? 2 * it + 3 : 31;      // addr clamp
    bf16x8 a0[4][2], a1[4][2], b0[2][2], b1[2][2];

    // ======== K-tile 2it (buf0) : phases 1-4 ========
    // ph1: A i0-3 + B j0-1 (12 reads) | stage B0(2it+1)->buf1
    rd4<0>(pAl, a0); rd2<0>(pBl, b0);
    stB(0, ktB, 1);
    asm volatile("s_waitcnt lgkmcnt(8)" ::: "memory");
    GQ_BAR();
    GQ_LGKM0();
    mm16<0, 0>(acc, a0, b0);
    GQ_BAR();

    // ph2: A i4-7 (8 reads) | stage B1(2it+1)->buf1
    rd4<4>(pAl, a1);
    stB(1, ktB, 1);
    GQ_BAR();
    GQ_LGKM0();
    mm16<4, 0>(acc, a1, b0);
    GQ_BAR();

    // ph3: B j2-3 (4 reads) | stage A0(2it+2)->buf0 (A reads done ph2)
    rd2<2>(pBl, b1);
    stA(0, kt2, 0);
    GQ_BAR();
    GQ_LGKM0();
    mm16<0, 2>(acc, a0, b1);
    GQ_BAR();

    // ph4: 0 reads | stage A1(2it+2)->buf0 | counted vmcnt for buf1
    stA(1, kt2, 0);
    GQ_BAR();
    mm16<4, 2>(acc, a1, b1);
    asm volatile("s_waitcnt vmcnt(4)" ::: "memory");
    GQ_BAR();
    GQ_FENCE();

    // ======== K-tile 2it+1 (buf1) : phases 5-8 ========
    const char* qAl = pAl + 32768;
    const char* qBl = pBl + 32768;

    // ph5: reads buf1 | stage B0(2it+2)->buf0 (B reads of buf0 done ph3)
    rd4<0>(qAl, a0); rd2<0>(qBl, b0);
    stB(0, kt2, 0);
    asm volatile("s_waitcnt lgkmcnt(8)" ::: "memory");
    GQ_BAR();
    GQ_LGKM0();
    mm16<0, 0>(acc, a0, b0);
    GQ_BAR();

    // ph6: A i4-7 | stage B1(2it+2)->buf0
    rd4<4>(qAl, a1);
    stB(1, kt2, 0);
    GQ_BAR();
    GQ_LGKM0();
    mm16<4, 0>(acc, a1, b0);
    GQ_BAR();

    // ph7: B j2-3 | stage A0(2it+3)->buf1 (buf1 A reads done ph6)
    rd2<2>(qBl, b1);
    stA(0, kt3, 1);
    GQ_BAR();
    GQ_LGKM0();
    mm16<0, 2>(acc, a0, b1);
    GQ_BAR();

    // ph8: 0 reads | stage A1(2it+3)->buf1 | counted vmcnt for next buf0
    stA(1, kt3, 1);
    GQ_BAR();
    mm16<4, 2>(acc, a1, b1);
    asm volatile("s_waitcnt vmcnt(4)" ::: "memory");
    GQ_BAR();
    GQ_FENCE();
  }

  // drain tail prefetches before epilogue / endpgm
  asm volatile("s_waitcnt vmcnt(0)" ::: "memory");

  // ---- epilogue: base select + fused RoPE (q scaled by 0.125) ----
  bf16_t* Cb; float qs; int dorope;
  if (bn0 < 2048)      { Cb = Cq; qs = 0.125f; dorope = 1; }
  else if (bn0 < 4096) { Cb = Ck; qs = 1.0f;   dorope = 1; }
  else                 { Cb = Cv; qs = 1.0f;   dorope = 0; }
  const int cb0 = (bn0 & 2047) + (wc << 6);
  const int rw0 = bm0 + wr * 128;

#pragma unroll
  for (int i = 0; i < 8; ++i) {
#pragma unroll
    for (int r = 0; r < 4; ++r) {
      const int row = rw0 + i * 16 + quad * 4 + r;
      const int t   = row & (T_ - 1);
#pragma unroll
      for (int j = 0; j < 4; ++j) {
        float v = acc[i][j][r];
        if (dorope) {                      // block-uniform branch
          const int hd = j * 16 + lane16;  // dim within head (col & 63)
          const float c  = fc[t * 32 + (hd >> 1)];
          const float s  = fs[t * 32 + (hd >> 1)];
          const float pr = __shfl_xor(v, 1);    // pair partner (col ^ 1)
          v = ((hd & 1) ? (pr * s + v * c) : (v * c - pr * s)) * qs;
        }
        Cb[(size_t)row * 2048 + cb0 + j * 16 + lane16] = (bf16_t)v;
      }
    }
  }
}

// ---------------------------------------------------------------------------
// RoPE in-place on bf16 q,k; folds 1/sqrt(64)=0.125 into q. (Path B only.)
// ---------------------------------------------------------------------------
__global__ __launch_bounds__(256) void rope_kernel(
    bf16_t* __restrict__ q, bf16_t* __restrict__ k,
    const float* __restrict__ cosb, const float* __restrict__ sinb, int npair)
{
  const int idx = blockIdx.x * 256 + threadIdx.x;
  if (idx >= npair) return;
  const int p = idx & 31;
  const int t = (idx >> 10) & (T_ - 1);
  const float c = cosb[t * 32 + p];
  const float s = sinb[t * 32 + p];
  const size_t off = (size_t)idx * 2;

  const float qr = (float)q[off], qi = (float)q[off + 1];
  q[off]     = (bf16_t)((qr * c - qi * s) * 0.125f);
  q[off + 1] = (bf16_t)((qr * s + qi * c) * 0.125f);

  const float kr = (float)k[off], ki = (float)k[off + 1];
  k[off]     = (bf16_t)(kr * c - ki * s);
  k[off + 1] = (bf16_t)(kr * s + ki * c);
}

// ---------------------------------------------------------------------------
// Flash attention v3 (causal, fixed-bias softmax, PAIRED q-groups).
// Block gx handles q-groups {gx*128, (15-gx)*128}: total work equal for all
// blocks (zero tail). 4 waves x 32 rows per group. 64-key steps; K/V staged
// once per step, consumed by both groups.
// ---------------------------------------------------------------------------
__global__ __launch_bounds__(256, 2) void flash_attn(
    const bf16_t* __restrict__ Q, const bf16_t* __restrict__ K,
    const bf16_t* __restrict__ V, bf16_t* __restrict__ Y)
{
  __shared__ __attribute__((aligned(16))) bf16_t Kf[4096];
  __shared__ __attribute__((aligned(16))) bf16_t Vf[4096];
  __shared__ __attribute__((aligned(16))) bf16_t Pt[4 * 2 * 16 * 68];

  const int tid    = threadIdx.x;
  const int w      = tid >> 6;
  const int l      = tid & 63;
  const int quad   = l >> 4;
  const int lane16 = l & 15;
  const int bh = blockIdx.y;
  const int b  = bh >> 5;
  const int h  = bh & 31;
  const int gx = blockIdx.x;            // 0..7
  int qa[2];
  qa[0] = gx * 128 + w * 32;            // light group
  qa[1] = (15 - gx) * 128 + w * 32;     // heavy group
  const size_t rs = (size_t)H_ * HD_;

  const bf16_t* Qb = Q + ((size_t)b * T_) * rs + h * HD_;
  const bf16_t* Kb = K + ((size_t)b * T_) * rs + h * HD_;
  const bf16_t* Vb = V + ((size_t)b * T_) * rs + h * HD_;

  // Q B-frags: [grp][tile][chunk]  n=lane16(q-row), k=quad*8+j(dim)
  bf16x8 qf[2][2][2];
#pragma unroll
  for (int g = 0; g < 2; ++g)
#pragma unroll
    for (int t = 0; t < 2; ++t)
#pragma unroll
      for (int c = 0; c < 2; ++c)
        qf[g][t][c] = *(const bf16x8*)(Qb + (size_t)(qa[g] + t * 16 + lane16) * rs +
                                       c * 32 + quad * 8);

  f32x4 o[2][2][4] = {};       // [grp][tile][dim-tile]
  float lsum[2][2] = {};       // [grp][tile], q-col = lane16, this quad's keys

  // staging assignment: thread = (key-offset, dim-octet)
  const int koff = tid >> 3;
  const int oct  = tid & 7;
  const int d0   = oct * 8;
  const int kc = oct >> 2, kq = oct & 3;
  const int nV = oct >> 1, base16 = (oct & 1) * 8;

  bf16_t* const PtW = Pt + w * (2 * 16 * 68);

  const int nsteps = (15 - gx) * 2 + 2;   // keys [0, (15-gx)*128 + 128)

  // prefetch step 0
  bf16x8 kr[2], vr[2];
#pragma unroll
  for (int hf = 0; hf < 2; ++hf) {
    const int key = hf * 32 + koff;
    kr[hf] = *(const bf16x8*)(Kb + (size_t)key * rs + d0);
    vr[hf] = *(const bf16x8*)(Vb + (size_t)key * rs + d0);
  }

  for (int it = 0; it < nsteps; ++it) {
    const int k0 = it * 64;
    __syncthreads();
#pragma unroll
    for (int hf = 0; hf < 2; ++hf) {
      const int key = hf * 32 + koff;
      const int gK = ((kc * 4 + (key >> 4)) * 16 + (key & 15)) * 4 + kq;
      *(bf16x8*)&Kf[gK * 8] = kr[hf];
      const int cV = key >> 5, qV = (key >> 3) & 3, jV = key & 7;
#pragma unroll
      for (int i = 0; i < 8; ++i) {
        const int gv = ((cV * 4 + nV) * 16 + base16 + i) * 4 + qV;
        Vf[(gv ^ oct) * 8 + jV] = vr[hf][i];
      }
    }
    __syncthreads();
    if (it + 1 < nsteps) {
      const int k0n = k0 + 64;
#pragma unroll
      for (int hf = 0; hf < 2; ++hf) {
        const int key = k0n + hf * 32 + koff;
        kr[hf] = *(const bf16x8*)(Kb + (size_t)key * rs + d0);
        vr[hf] = *(const bf16x8*)(Vb + (size_t)key * rs + d0);
      }
    }

#pragma unroll
    for (int g = 0; g < 2; ++g) {
      if (k0 > qa[g] + 31) continue;       // group fully masked (wave-uniform)

      // ---- S^T = K.Q^T ----
      f32x4 stx[4][2] = {};
#pragma unroll
      for (int c = 0; c < 2; ++c) {
#pragma unroll
        for (int kt = 0; kt < 4; ++kt) {
          const bf16x8 kfr =
              *(const bf16x8*)&Kf[(((c * 4 + kt) * 16 + lane16) * 4 + quad) * 8];
          stx[kt][0] = __builtin_amdgcn_mfma_f32_16x16x32_bf16(kfr, qf[g][0][c],
                                                               stx[kt][0], 0, 0, 0);
          stx[kt][1] = __builtin_amdgcn_mfma_f32_16x16x32_bf16(kfr, qf[g][1][c],
                                                               stx[kt][1], 0, 0, 0);
        }
      }

      // ---- softmax numerator (no max; s bounded ~|q||k|/8) ----
#pragma unroll
      for (int t = 0; t < 2; ++t) {
        const int qbase = qa[g] + t * 16;
#pragma unroll
        for (int kt = 0; kt < 4; ++kt) {
          const int kbase = k0 + kt * 16 + quad * 4;
          const bool anymask = (k0 + kt * 16 + 15) > qbase;   // wave-uniform
          float p[4];
#pragma unroll
          for (int r = 0; r < 4; ++r) {
            float s = stx[kt][t][r];
            if (anymask) s = (kbase + r > qbase + lane16) ? -1e30f : s;
            p[r] = __expf(s);
          }
          lsum[g][t] += (p[0] + p[1]) + (p[2] + p[3]);
          bf16x4 pv;
          pv[0] = (bf16_t)p[0]; pv[1] = (bf16_t)p[1];
          pv[2] = (bf16_t)p[2]; pv[3] = (bf16_t)p[3];
          *(bf16x4*)&PtW[(t * 16 + lane16) * 68 + kt * 16 + quad * 4] = pv;
        }
      }

      // ---- O += P.V ----
#pragma unroll
      for (int c = 0; c < 2; ++c) {
        const bf16x8 pf0 = *(const bf16x8*)&PtW[(0 * 16 + lane16) * 68 + c * 32 + quad * 8];
        const bf16x8 pf1 = *(const bf16x8*)&PtW[(1 * 16 + lane16) * 68 + c * 32 + quad * 8];
#pragma unroll
        for (int n = 0; n < 4; ++n) {
          const int gv = ((c * 4 + n) * 16 + lane16) * 4 + quad;
          const int swz = n * 2 + (lane16 >> 3);
          const bf16x8 vfr = *(const bf16x8*)&Vf[(gv ^ swz) * 8];
          o[g][0][n] = __builtin_amdgcn_mfma_f32_16x16x32_bf16(pf0, vfr, o[g][0][n], 0, 0, 0);
          o[g][1][n] = __builtin_amdgcn_mfma_f32_16x16x32_bf16(pf1, vfr, o[g][1][n], 0, 0, 0);
        }
      }
    }
  }

  // ---- epilogue ----
  bf16_t* Yb = Y + ((size_t)b * T_) * rs + h * HD_;
#pragma unroll
  for (int g = 0; g < 2; ++g) {
#pragma unroll
    for (int t = 0; t < 2; ++t) {
      float lt = lsum[g][t];
      lt += __shfl_xor(lt, 16);
      lt += __shfl_xor(lt, 32);
#pragma unroll
      for (int r = 0; r < 4; ++r) {
        const float linv = 1.0f / __shfl(lt, quad * 4 + r);
        const size_t row = (size_t)(qa[g] + t * 16 + quad * 4 + r);
#pragma unroll
        for (int n = 0; n < 4; ++n)
          Yb[row * rs + n * 16 + lane16] = (bf16_t)(o[g][t][n][r] * linv);
      }
    }
  }
}

// ---------------------------------------------------------------------------
extern "C" void kernel_launch(void* const* d_in, const int* in_sizes, int n_in,
                              void* d_out, int out_size, void* d_ws, size_t ws_size,
                              hipStream_t stream)
{
  (void)in_sizes; (void)n_in; (void)out_size;
  const float* x  = (const float*)d_in[0];
  const float* fc = (const float*)d_in[1];
  const float* fs = (const float*)d_in[2];
  const float* wq = (const float*)d_in[3];
  const float* wk = (const float*)d_in[4];
  const float* wv = (const float*)d_in[5];
  const float* wo = (const float*)d_in[6];
  float* out = (float*)d_out;

  const size_t nx = (size_t)M_ * D_;        // 8.39M
  const size_t nw = (size_t)D_ * D_;        // 4.19M
  const dim3 blk(256);
  const int nx4 = (int)(nx / 4), nw4 = (int)(nw / 4);
  const dim3 gg(M_ / 128, D_ / 128);        // 32 x 16

  if (ws_size >= (3 * nw + 4 * nx) * sizeof(bf16_t)) {
    // ---- Path A: 8-phase merged QKV gemm + fused RoPE (needs 92.3 MB ws) ----
    // layout: wb3[3*nw] | xb[nx] | qb[nx] | kb[nx] | vb[nx]; yb aliases xb.
    bf16_t* ws  = (bf16_t*)d_ws;
    bf16_t* wb3 = ws;
    bf16_t* xb  = ws + 3 * nw;
    bf16_t* qb  = xb + nx;
    bf16_t* kb  = qb + nx;
    bf16_t* vb  = kb + nx;
    bf16_t* yb  = xb;

    cast_f32_bf16<<<dim3(nx4 / 256), blk, 0, stream>>>(x, xb, nx4);
    cast_f32_bf16<<<dim3(nw4 / 256), blk, 0, stream>>>(wq, wb3, nw4);
    cast_f32_bf16<<<dim3(nw4 / 256), blk, 0, stream>>>(wk, wb3 + nw, nw4);
    cast_f32_bf16<<<dim3(nw4 / 256), blk, 0, stream>>>(wv, wb3 + 2 * nw, nw4);

    gemm_qkv8<<<dim3(384), dim3(512), 0, stream>>>(xb, wb3, qb, kb, vb, fc, fs);

    flash_attn<<<dim3(8, B_ * H_), blk, 0, stream>>>(qb, kb, vb, yb);

    cast_f32_bf16<<<dim3(nw4 / 256), blk, 0, stream>>>(wo, wb3, nw4);
    gemm_bt<float><<<gg, blk, 0, stream>>>(yb, wb3, out, M_, D_, D_);
  } else {
    // ---- Path B: r3 serial 3-gemm (75.5 MB ws) ----
    bf16_t* ws = (bf16_t*)d_ws;
    bf16_t* wb = ws;
    bf16_t* xb = ws + nw;
    bf16_t* qb = xb + nx;
    bf16_t* kb = qb + nx;
    bf16_t* vb = kb + nx;
    bf16_t* yb = xb;

    cast_f32_bf16<<<dim3(nx4 / 256), blk, 0, stream>>>(x, xb, nx4);
    cast_f32_bf16<<<dim3(nw4 / 256), blk, 0, stream>>>(wq, wb, nw4);
    gemm_bt<bf16_t><<<gg, blk, 0, stream>>>(xb, wb, qb, M_, D_, D_);
    cast_f32_bf16<<<dim3(nw4 / 256), blk, 0, stream>>>(wk, wb, nw4);
    gemm_bt<bf16_t><<<gg, blk, 0, stream>>>(xb, wb, kb, M_, D_, D_);
    cast_f32_bf16<<<dim3(nw4 / 256), blk, 0, stream>>>(wv, wb, nw4);
    gemm_bt<bf16_t><<<gg, blk, 0, stream>>>(xb, wb, vb, M_, D_, D_);

    rope_kernel<<<dim3((B_ * T_ * H_ * 32) / 256), blk, 0, stream>>>(
        qb, kb, fc, fs, B_ * T_ * H_ * 32);
    flash_attn<<<dim3(8, B_ * H_), blk, 0, stream>>>(qb, kb, vb, yb);

    cast_f32_bf16<<<dim3(nw4 / 256), blk, 0, stream>>>(wo, wb, nw4);
    gemm_bt<float><<<gg, blk, 0, stream>>>(yb, wb, out, M_, D_, D_);
  }
}

// Round 3
// 409.140 us; speedup vs baseline: 1.0552x; 1.0552x over previous
//
#include <hip/hip_runtime.h>
#include <hip/hip_bf16.h>
#include <stdint.h>

// ---------------------------------------------------------------------------
// AttentionBlock: y = Attn(RoPE(x@wq^T), RoPE(x@wk^T), x@wv^T) @ wo^T
// B=2 T=2048 D=2048 H=32 HD=64. FP32 in/out, bf16 MFMA internal.
//
// r5 -> r6 post-mortem: the 8-phase 256^2 rewrite REGRESSED (176.9us vs
// 135.8us, MfmaUtil 24% vs 33%, all pipes idle). Bank conflicts did go
// 1.26e7 -> 0 (T2 verified), but: (a) 128KiB LDS + grid 384 on 256 CUs = 2
// scheduling rounds, round 2 half-empty (~25% loss); (b) my phase schedule
// could only issue B half-tiles 2-3 phases (~500cy) before their vmcnt
// drain < 900cy HBM latency -> structural stall every K-tile. m201's depth
// (>=4 phases) needs a slot schedule I can't reconstruct blind.
// r6: revert to the MEASURED m97-style gemm_qkv (135.8us) and keep the
// verified piece of r5: RoPE (+0.125 q-scale) fused into the gemm epilogue
// via __shfl_xor(v,1) lane pairing (numerics validated in r5, absmax
// unchanged). rope_kernel dispatch removed from Path A.
// ---------------------------------------------------------------------------

typedef __bf16 bf16_t;
typedef __bf16 bf16x4 __attribute__((ext_vector_type(4)));
typedef __bf16 bf16x8 __attribute__((ext_vector_type(8)));
typedef float  f32x4  __attribute__((ext_vector_type(4)));

constexpr int B_ = 2, T_ = 2048, D_ = 2048, H_ = 32, HD_ = 64;
constexpr int M_ = B_ * T_;   // 4096 token rows

// async global->LDS, 16B per lane; LDS dest = wave-uniform base + lane*16
__device__ __forceinline__ void async_copy16(const bf16_t* g, bf16_t* l) {
  __builtin_amdgcn_global_load_lds(
      (const __attribute__((address_space(1))) void*)g,
      (__attribute__((address_space(3))) void*)l, 16, 0, 0);
}

// ---------------------------------------------------------------------------
// f32 -> bf16 cast, 4 elements/thread.
// ---------------------------------------------------------------------------
__global__ __launch_bounds__(256) void cast_f32_bf16(
    const float* __restrict__ src, bf16_t* __restrict__ dst, int n4)
{
  const int i = blockIdx.x * 256 + threadIdx.x;
  if (i >= n4) return;
  const float4 v = ((const float4*)src)[i];
  bf16x4 o;
  o[0] = (bf16_t)v.x; o[1] = (bf16_t)v.y; o[2] = (bf16_t)v.z; o[3] = (bf16_t)v.w;
  ((bf16x4*)dst)[i] = o;
}

// ---------------------------------------------------------------------------
// GEMM: C[M][N] = A[M][K] . B[N][K]^T — m97 structure (wo-gemm + Path B).
// ---------------------------------------------------------------------------
template <typename OutT>
__global__ __launch_bounds__(256, 2) void gemm_bt(
    const bf16_t* __restrict__ A, const bf16_t* __restrict__ B,
    OutT* __restrict__ C, int M, int N, int K)
{
  __shared__ __attribute__((aligned(16))) bf16_t As[128 * 32];
  __shared__ __attribute__((aligned(16))) bf16_t Bs[128 * 32];

  const int tid    = threadIdx.x;
  const int w      = tid >> 6;
  const int l      = tid & 63;
  const int quad   = l >> 4;
  const int lane16 = l & 15;
  const int bm0 = blockIdx.x * 128;
  const int bn0 = blockIdx.y * 128;
  const int wm  = (w >> 1) * 64;
  const int wn  = (w & 1) * 64;
  const int srow = l >> 2;
  const int scol = (l & 3) * 8;

  const bf16_t* Ag = A + (size_t)bm0 * K;
  const bf16_t* Bg = B + (size_t)bn0 * K;

  f32x4 acc[4][4] = {};

  for (int kk = 0; kk < K; kk += 32) {
    __syncthreads();
#pragma unroll
    for (int s0 = 0; s0 < 2; ++s0) {
      const int s = w + s0 * 4;
      async_copy16(Ag + (size_t)(s * 16 + srow) * K + kk + scol, &As[s * 512]);
      async_copy16(Bg + (size_t)(s * 16 + srow) * K + kk + scol, &Bs[s * 512]);
    }
    __syncthreads();

    bf16x8 af[4], bfr[4];
#pragma unroll
    for (int i = 0; i < 4; ++i)
      af[i] = *(const bf16x8*)&As[(wm + i * 16 + lane16) * 32 + quad * 8];
#pragma unroll
    for (int j = 0; j < 4; ++j)
      bfr[j] = *(const bf16x8*)&Bs[(wn + j * 16 + lane16) * 32 + quad * 8];
#pragma unroll
    for (int i = 0; i < 4; ++i)
#pragma unroll
      for (int j = 0; j < 4; ++j)
        acc[i][j] = __builtin_amdgcn_mfma_f32_16x16x32_bf16(af[i], bfr[j],
                                                            acc[i][j], 0, 0, 0);
  }

#pragma unroll
  for (int i = 0; i < 4; ++i) {
#pragma unroll
    for (int r = 0; r < 4; ++r) {
      const size_t row = (size_t)(bm0 + wm + i * 16 + quad * 4 + r);
#pragma unroll
      for (int j = 0; j < 4; ++j) {
        const int col = bn0 + wn + j * 16 + lane16;
        C[row * N + col] = (OutT)acc[i][j][r];
      }
    }
  }
}

// ---------------------------------------------------------------------------
// Merged-QKV GEMM (m97 structure, measured 135.8us) + fused RoPE epilogue.
// B = concat(wq|wk|wv) [6144][2048]; epilogue base-selects into compact
// q/k/v buffers (each [M][2048]) and applies RoPE to q (x0.125) and k.
// Grid (M/128, 48).
// ---------------------------------------------------------------------------
__global__ __launch_bounds__(256, 2) void gemm_qkv(
    const bf16_t* __restrict__ A, const bf16_t* __restrict__ B,
    bf16_t* __restrict__ Cq, bf16_t* __restrict__ Ck, bf16_t* __restrict__ Cv,
    const float* __restrict__ fc, const float* __restrict__ fs,
    int M, int K)
{
  __shared__ __attribute__((aligned(16))) bf16_t As[128 * 32];
  __shared__ __attribute__((aligned(16))) bf16_t Bs[128 * 32];

  const int tid    = threadIdx.x;
  const int w      = tid >> 6;
  const int l      = tid & 63;
  const int quad   = l >> 4;
  const int lane16 = l & 15;
  const int bm0 = blockIdx.x * 128;
  const int bn0 = blockIdx.y * 128;
  const int wm  = (w >> 1) * 64;
  const int wn  = (w & 1) * 64;
  const int srow = l >> 2;
  const int scol = (l & 3) * 8;

  const bf16_t* Ag = A + (size_t)bm0 * K;
  const bf16_t* Bg = B + (size_t)bn0 * K;

  f32x4 acc[4][4] = {};

  for (int kk = 0; kk < K; kk += 32) {
    __syncthreads();
#pragma unroll
    for (int s0 = 0; s0 < 2; ++s0) {
      const int s = w + s0 * 4;
      async_copy16(Ag + (size_t)(s * 16 + srow) * K + kk + scol, &As[s * 512]);
      async_copy16(Bg + (size_t)(s * 16 + srow) * K + kk + scol, &Bs[s * 512]);
    }
    __syncthreads();

    bf16x8 af[4], bfr[4];
#pragma unroll
    for (int i = 0; i < 4; ++i)
      af[i] = *(const bf16x8*)&As[(wm + i * 16 + lane16) * 32 + quad * 8];
#pragma unroll
    for (int j = 0; j < 4; ++j)
      bfr[j] = *(const bf16x8*)&Bs[(wn + j * 16 + lane16) * 32 + quad * 8];
#pragma unroll
    for (int i = 0; i < 4; ++i)
#pragma unroll
      for (int j = 0; j < 4; ++j)
        acc[i][j] = __builtin_amdgcn_mfma_f32_16x16x32_bf16(af[i], bfr[j],
                                                            acc[i][j], 0, 0, 0);
  }

  // ---- epilogue: base select + fused RoPE (q scaled by 1/sqrt(HD)) ----
  // col within head hd = j*16+lane16 (wn adds a multiple of 64 -> drops out).
  // Pair partner col^1 lives in lane^1 (same row: row depends on quad,r
  // only) -> __shfl_xor(v,1). Even hd: xr' = xr*c - xi*s; odd: xi' =
  // xr*s + xi*c. dorope is block-uniform; all shfl in uniform flow.
  bf16_t* Cb; float qs; int dorope;
  if (bn0 < 2048)      { Cb = Cq; qs = 0.125f; dorope = 1; }
  else if (bn0 < 4096) { Cb = Ck; qs = 1.0f;   dorope = 1; }
  else                 { Cb = Cv; qs = 1.0f;   dorope = 0; }
  const int cb0 = (bn0 & 2047) + wn;
#pragma unroll
  for (int i = 0; i < 4; ++i) {
#pragma unroll
    for (int r = 0; r < 4; ++r) {
      const size_t row = (size_t)(bm0 + wm + i * 16 + quad * 4 + r);
      const int t = (int)(row & (T_ - 1));
#pragma unroll
      for (int j = 0; j < 4; ++j) {
        float v = acc[i][j][r];
        if (dorope) {                      // block-uniform branch
          const int hd = j * 16 + lane16;  // dim within head
          const float c  = fc[t * 32 + (hd >> 1)];
          const float s  = fs[t * 32 + (hd >> 1)];
          const float pr = __shfl_xor(v, 1);    // pair partner (col ^ 1)
          v = ((hd & 1) ? (pr * s + v * c) : (v * c - pr * s)) * qs;
        }
        Cb[row * 2048 + cb0 + j * 16 + lane16] = (bf16_t)v;
      }
    }
  }
}

// ---------------------------------------------------------------------------
// RoPE in-place on bf16 q,k; folds 1/sqrt(64)=0.125 into q. (Path B only.)
// ---------------------------------------------------------------------------
__global__ __launch_bounds__(256) void rope_kernel(
    bf16_t* __restrict__ q, bf16_t* __restrict__ k,
    const float* __restrict__ cosb, const float* __restrict__ sinb, int npair)
{
  const int idx = blockIdx.x * 256 + threadIdx.x;
  if (idx >= npair) return;
  const int p = idx & 31;
  const int t = (idx >> 10) & (T_ - 1);
  const float c = cosb[t * 32 + p];
  const float s = sinb[t * 32 + p];
  const size_t off = (size_t)idx * 2;

  const float qr = (float)q[off], qi = (float)q[off + 1];
  q[off]     = (bf16_t)((qr * c - qi * s) * 0.125f);
  q[off + 1] = (bf16_t)((qr * s + qi * c) * 0.125f);

  const float kr = (float)k[off], ki = (float)k[off + 1];
  k[off]     = (bf16_t)(kr * c - ki * s);
  k[off + 1] = (bf16_t)(kr * s + ki * c);
}

// ---------------------------------------------------------------------------
// Flash attention v3 (causal, fixed-bias softmax, PAIRED q-groups).
// Block gx handles q-groups {gx*128, (15-gx)*128}: total work equal for all
// blocks (zero tail). 4 waves x 32 rows per group. 64-key steps; K/V staged
// once per step, consumed by both groups.
// ---------------------------------------------------------------------------
__global__ __launch_bounds__(256, 2) void flash_attn(
    const bf16_t* __restrict__ Q, const bf16_t* __restrict__ K,
    const bf16_t* __restrict__ V, bf16_t* __restrict__ Y)
{
  __shared__ __attribute__((aligned(16))) bf16_t Kf[4096];
  __shared__ __attribute__((aligned(16))) bf16_t Vf[4096];
  __shared__ __attribute__((aligned(16))) bf16_t Pt[4 * 2 * 16 * 68];

  const int tid    = threadIdx.x;
  const int w      = tid >> 6;
  const int l      = tid & 63;
  const int quad   = l >> 4;
  const int lane16 = l & 15;
  const int bh = blockIdx.y;
  const int b  = bh >> 5;
  const int h  = bh & 31;
  const int gx = blockIdx.x;            // 0..7
  int qa[2];
  qa[0] = gx * 128 + w * 32;            // light group
  qa[1] = (15 - gx) * 128 + w * 32;     // heavy group
  const size_t rs = (size_t)H_ * HD_;

  const bf16_t* Qb = Q + ((size_t)b * T_) * rs + h * HD_;
  const bf16_t* Kb = K + ((size_t)b * T_) * rs + h * HD_;
  const bf16_t* Vb = V + ((size_t)b * T_) * rs + h * HD_;

  // Q B-frags: [grp][tile][chunk]  n=lane16(q-row), k=quad*8+j(dim)
  bf16x8 qf[2][2][2];
#pragma unroll
  for (int g = 0; g < 2; ++g)
#pragma unroll
    for (int t = 0; t < 2; ++t)
#pragma unroll
      for (int c = 0; c < 2; ++c)
        qf[g][t][c] = *(const bf16x8*)(Qb + (size_t)(qa[g] + t * 16 + lane16) * rs +
                                       c * 32 + quad * 8);

  f32x4 o[2][2][4] = {};       // [grp][tile][dim-tile]
  float lsum[2][2] = {};       // [grp][tile], q-col = lane16, this quad's keys

  // staging assignment: thread = (key-offset, dim-octet)
  const int koff = tid >> 3;
  const int oct  = tid & 7;
  const int d0   = oct * 8;
  const int kc = oct >> 2, kq = oct & 3;
  const int nV = oct >> 1, base16 = (oct & 1) * 8;

  bf16_t* const PtW = Pt + w * (2 * 16 * 68);

  const int nsteps = (15 - gx) * 2 + 2;   // keys [0, (15-gx)*128 + 128)

  // prefetch step 0
  bf16x8 kr[2], vr[2];
#pragma unroll
  for (int hf = 0; hf < 2; ++hf) {
    const int key = hf * 32 + koff;
    kr[hf] = *(const bf16x8*)(Kb + (size_t)key * rs + d0);
    vr[hf] = *(const bf16x8*)(Vb + (size_t)key * rs + d0);
  }

  for (int it = 0; it < nsteps; ++it) {
    const int k0 = it * 64;
    __syncthreads();
#pragma unroll
    for (int hf = 0; hf < 2; ++hf) {
      const int key = hf * 32 + koff;
      const int gK = ((kc * 4 + (key >> 4)) * 16 + (key & 15)) * 4 + kq;
      *(bf16x8*)&Kf[gK * 8] = kr[hf];
      const int cV = key >> 5, qV = (key >> 3) & 3, jV = key & 7;
#pragma unroll
      for (int i = 0; i < 8; ++i) {
        const int gv = ((cV * 4 + nV) * 16 + base16 + i) * 4 + qV;
        Vf[(gv ^ oct) * 8 + jV] = vr[hf][i];
      }
    }
    __syncthreads();
    if (it + 1 < nsteps) {
      const int k0n = k0 + 64;
#pragma unroll
      for (int hf = 0; hf < 2; ++hf) {
        const int key = k0n + hf * 32 + koff;
        kr[hf] = *(const bf16x8*)(Kb + (size_t)key * rs + d0);
        vr[hf] = *(const bf16x8*)(Vb + (size_t)key * rs + d0);
      }
    }

#pragma unroll
    for (int g = 0; g < 2; ++g) {
      if (k0 > qa[g] + 31) continue;       // group fully masked (wave-uniform)

      // ---- S^T = K.Q^T ----
      f32x4 stx[4][2] = {};
#pragma unroll
      for (int c = 0; c < 2; ++c) {
#pragma unroll
        for (int kt = 0; kt < 4; ++kt) {
          const bf16x8 kfr =
              *(const bf16x8*)&Kf[(((c * 4 + kt) * 16 + lane16) * 4 + quad) * 8];
          stx[kt][0] = __builtin_amdgcn_mfma_f32_16x16x32_bf16(kfr, qf[g][0][c],
                                                               stx[kt][0], 0, 0, 0);
          stx[kt][1] = __builtin_amdgcn_mfma_f32_16x16x32_bf16(kfr, qf[g][1][c],
                                                               stx[kt][1], 0, 0, 0);
        }
      }

      // ---- softmax numerator (no max; s bounded ~|q||k|/8) ----
#pragma unroll
      for (int t = 0; t < 2; ++t) {
        const int qbase = qa[g] + t * 16;
#pragma unroll
        for (int kt = 0; kt < 4; ++kt) {
          const int kbase = k0 + kt * 16 + quad * 4;
          const bool anymask = (k0 + kt * 16 + 15) > qbase;   // wave-uniform
          float p[4];
#pragma unroll
          for (int r = 0; r < 4; ++r) {
            float s = stx[kt][t][r];
            if (anymask) s = (kbase + r > qbase + lane16) ? -1e30f : s;
            p[r] = __expf(s);
          }
          lsum[g][t] += (p[0] + p[1]) + (p[2] + p[3]);
          bf16x4 pv;
          pv[0] = (bf16_t)p[0]; pv[1] = (bf16_t)p[1];
          pv[2] = (bf16_t)p[2]; pv[3] = (bf16_t)p[3];
          *(bf16x4*)&PtW[(t * 16 + lane16) * 68 + kt * 16 + quad * 4] = pv;
        }
      }

      // ---- O += P.V ----
#pragma unroll
      for (int c = 0; c < 2; ++c) {
        const bf16x8 pf0 = *(const bf16x8*)&PtW[(0 * 16 + lane16) * 68 + c * 32 + quad * 8];
        const bf16x8 pf1 = *(const bf16x8*)&PtW[(1 * 16 + lane16) * 68 + c * 32 + quad * 8];
#pragma unroll
        for (int n = 0; n < 4; ++n) {
          const int gv = ((c * 4 + n) * 16 + lane16) * 4 + quad;
          const int swz = n * 2 + (lane16 >> 3);
          const bf16x8 vfr = *(const bf16x8*)&Vf[(gv ^ swz) * 8];
          o[g][0][n] = __builtin_amdgcn_mfma_f32_16x16x32_bf16(pf0, vfr, o[g][0][n], 0, 0, 0);
          o[g][1][n] = __builtin_amdgcn_mfma_f32_16x16x32_bf16(pf1, vfr, o[g][1][n], 0, 0, 0);
        }
      }
    }
  }

  // ---- epilogue ----
  bf16_t* Yb = Y + ((size_t)b * T_) * rs + h * HD_;
#pragma unroll
  for (int g = 0; g < 2; ++g) {
#pragma unroll
    for (int t = 0; t < 2; ++t) {
      float lt = lsum[g][t];
      lt += __shfl_xor(lt, 16);
      lt += __shfl_xor(lt, 32);
#pragma unroll
      for (int r = 0; r < 4; ++r) {
        const float linv = 1.0f / __shfl(lt, quad * 4 + r);
        const size_t row = (size_t)(qa[g] + t * 16 + quad * 4 + r);
#pragma unroll
        for (int n = 0; n < 4; ++n)
          Yb[row * rs + n * 16 + lane16] = (bf16_t)(o[g][t][n][r] * linv);
      }
    }
  }
}

// ---------------------------------------------------------------------------
extern "C" void kernel_launch(void* const* d_in, const int* in_sizes, int n_in,
                              void* d_out, int out_size, void* d_ws, size_t ws_size,
                              hipStream_t stream)
{
  (void)in_sizes; (void)n_in; (void)out_size;
  const float* x  = (const float*)d_in[0];
  const float* fc = (const float*)d_in[1];
  const float* fs = (const float*)d_in[2];
  const float* wq = (const float*)d_in[3];
  const float* wk = (const float*)d_in[4];
  const float* wv = (const float*)d_in[5];
  const float* wo = (const float*)d_in[6];
  float* out = (float*)d_out;

  const size_t nx = (size_t)M_ * D_;        // 8.39M
  const size_t nw = (size_t)D_ * D_;        // 4.19M
  const dim3 blk(256);
  const int nx4 = (int)(nx / 4), nw4 = (int)(nw / 4);
  const dim3 gg(M_ / 128, D_ / 128);        // 32 x 16

  if (ws_size >= (3 * nw + 4 * nx) * sizeof(bf16_t)) {
    // ---- Path A: merged QKV gemm + fused RoPE (needs 92.3 MB ws) ----
    // layout: wb3[3*nw] | xb[nx] | qb[nx] | kb[nx] | vb[nx]; yb aliases xb.
    bf16_t* ws  = (bf16_t*)d_ws;
    bf16_t* wb3 = ws;
    bf16_t* xb  = ws + 3 * nw;
    bf16_t* qb  = xb + nx;
    bf16_t* kb  = qb + nx;
    bf16_t* vb  = kb + nx;
    bf16_t* yb  = xb;

    cast_f32_bf16<<<dim3(nx4 / 256), blk, 0, stream>>>(x, xb, nx4);
    cast_f32_bf16<<<dim3(nw4 / 256), blk, 0, stream>>>(wq, wb3, nw4);
    cast_f32_bf16<<<dim3(nw4 / 256), blk, 0, stream>>>(wk, wb3 + nw, nw4);
    cast_f32_bf16<<<dim3(nw4 / 256), blk, 0, stream>>>(wv, wb3 + 2 * nw, nw4);

    gemm_qkv<<<dim3(M_ / 128, 48), blk, 0, stream>>>(xb, wb3, qb, kb, vb,
                                                     fc, fs, M_, D_);

    flash_attn<<<dim3(8, B_ * H_), blk, 0, stream>>>(qb, kb, vb, yb);

    cast_f32_bf16<<<dim3(nw4 / 256), blk, 0, stream>>>(wo, wb3, nw4);
    gemm_bt<float><<<gg, blk, 0, stream>>>(yb, wb3, out, M_, D_, D_);
  } else {
    // ---- Path B: serial 3-gemm (75.5 MB ws) ----
    bf16_t* ws = (bf16_t*)d_ws;
    bf16_t* wb = ws;
    bf16_t* xb = ws + nw;
    bf16_t* qb = xb + nx;
    bf16_t* kb = qb + nx;
    bf16_t* vb = kb + nx;
    bf16_t* yb = xb;

    cast_f32_bf16<<<dim3(nx4 / 256), blk, 0, stream>>>(x, xb, nx4);
    cast_f32_bf16<<<dim3(nw4 / 256), blk, 0, stream>>>(wq, wb, nw4);
    gemm_bt<bf16_t><<<gg, blk, 0, stream>>>(xb, wb, qb, M_, D_, D_);
    cast_f32_bf16<<<dim3(nw4 / 256), blk, 0, stream>>>(wk, wb, nw4);
    gemm_bt<bf16_t><<<gg, blk, 0, stream>>>(xb, wb, kb, M_, D_, D_);
    cast_f32_bf16<<<dim3(nw4 / 256), blk, 0, stream>>>(wv, wb, nw4);
    gemm_bt<bf16_t><<<gg, blk, 0, stream>>>(xb, wb, vb, M_, D_, D_);

    rope_kernel<<<dim3((B_ * T_ * H_ * 32) / 256), blk, 0, stream>>>(
        qb, kb, fc, fs, B_ * T_ * H_ * 32);
    flash_attn<<<dim3(8, B_ * H_), blk, 0, stream>>>(qb, kb, vb, yb);

    cast_f32_bf16<<<dim3(nw4 / 256), blk, 0, stream>>>(wo, wb, nw4);
    gemm_bt<float><<<gg, blk, 0, stream>>>(yb, wb, out, M_, D_, D_);
  }
}